// Round 2
// baseline (131.939 us; speedup 1.0000x reference)
//
#include <hip/hip_runtime.h>
#include <hip/hip_bf16.h>

#define B_ 16
#define T_ 4096
#define IN_ 2
#define H_ 256
#define N_ 256

#define TWO_PI_F 6.28318530717958647692f
#define INV_TWO_PI_D 0.15915494309189533576888376337251

// ---------------------------------------------------------------------------
// Kernel A: blocks [0,N_):   Cw[n] = sum_h Wh[h] * (C_re[h,n] + i C_im[h,n])
//           blocks [N_,N_+B_): out[b] = bh + sum_h Wh[h]*(D[h,:].x[b,t*,:])
// 256 threads, one h per thread, block reduce.
// ---------------------------------------------------------------------------
__global__ __launch_bounds__(256) void setup_kernel(
        const float* __restrict__ C_re, const float* __restrict__ C_im,
        const float* __restrict__ Wh, const float* __restrict__ bh,
        const float* __restrict__ D, const float* __restrict__ x,
        const int* __restrict__ lengths,
        float2* __restrict__ Cw, float* __restrict__ out) {
    __shared__ float2 sred[4];
    int h = threadIdx.x;
    int wid = threadIdx.x >> 6;
    int lane = threadIdx.x & 63;
    float w = Wh[h];

    if (blockIdx.x < N_) {
        int n = blockIdx.x;
        float vr = w * C_re[h * N_ + n];
        float vi = w * C_im[h * N_ + n];
        for (int off = 32; off > 0; off >>= 1) {
            vr += __shfl_down(vr, off);
            vi += __shfl_down(vi, off);
        }
        if (lane == 0) sred[wid] = make_float2(vr, vi);
        __syncthreads();
        if (threadIdx.x == 0) {
            float2 t = sred[0];
            t.x += sred[1].x + sred[2].x + sred[3].x;
            t.y += sred[1].y + sred[2].y + sred[3].y;
            Cw[n] = t;
        }
    } else {
        int b = blockIdx.x - N_;
        int tstar = lengths[b] - 1;
        float2 xv = ((const float2*)x)[(size_t)b * T_ + tstar];
        float v = w * (D[2 * h] * xv.x + D[2 * h + 1] * xv.y);
        for (int off = 32; off > 0; off >>= 1) v += __shfl_down(v, off);
        if (lane == 0) sred[wid] = make_float2(v, 0.f);
        __syncthreads();
        if (threadIdx.x == 0) {
            out[b] = sred[0].x + sred[1].x + sred[2].x + sred[3].x + bh[0];
        }
    }
}

// ---------------------------------------------------------------------------
// Kernel B: per (n,b) block: w_i = sum_{s<=t*} lam_n^{t*-s} x[b,s,i]
// via per-thread geometric recurrence: thread tid owns s = tid (mod 256),
// iterates s descending from s0 (k ascending), factor *= lam^256 per step.
// Then state = gamma*(Bm0*w0 + Bm1*w1); atomicAdd(out+b, Re(state*Cw[n])).
// ---------------------------------------------------------------------------
__global__ __launch_bounds__(256) void lru_kernel(
        const float* __restrict__ x, const int* __restrict__ lengths,
        const float* __restrict__ nu_log, const float* __restrict__ theta_log,
        const float* __restrict__ B_re, const float* __restrict__ B_im,
        const float2* __restrict__ Cw, float* __restrict__ out) {
    const int n = blockIdx.x;
    const int b = blockIdx.y;
    const int tid = threadIdx.x;
    const int tstar = lengths[b] - 1;

    const float nu = __expf(nu_log[n]);
    const float th = __expf(theta_log[n]);
    const double threv = (double)th * INV_TWO_PI_D;  // theta / 2pi

    const float2* xb = ((const float2*)x) + (size_t)b * T_;

    float a0r = 0.f, a0i = 0.f, a1r = 0.f, a1i = 0.f;
    if (tid <= tstar) {
        const int k0 = (tstar - tid) & 255;          // initial exponent (0..255)
        const int s0 = tstar - k0;                   // s0 = tid + 256*jmax
        // factor = lam^k0  (one fp64 phase reduction, once per thread)
        double f0 = (double)k0 * threv;
        float ang0 = (float)(f0 - rint(f0)) * TWO_PI_F;
        float sn, cs;
        __sincosf(ang0, &sn, &cs);
        float e0 = __expf(-(float)k0 * nu);
        float fr = e0 * cs, fi = e0 * sn;
        // rot = lam^256
        double f2 = 256.0 * threv;
        float ang2 = (float)(f2 - rint(f2)) * TWO_PI_F;
        __sincosf(ang2, &sn, &cs);
        float e2 = __expf(-256.f * nu);              // underflow to 0 is fine
        float rr = e2 * cs, ri = e2 * sn;

        for (int s = s0; s >= 0; s -= 256) {
            float2 xv = xb[s];
            a0r = fmaf(fr, xv.x, a0r);
            a0i = fmaf(fi, xv.x, a0i);
            a1r = fmaf(fr, xv.y, a1r);
            a1i = fmaf(fi, xv.y, a1i);
            float nfr = fr * rr - fi * ri;           // factor *= rot
            float nfi = fmaf(fr, ri, fi * rr);
            fr = nfr;
            fi = nfi;
        }
    }

    // block-reduce 4 floats
    for (int off = 32; off > 0; off >>= 1) {
        a0r += __shfl_down(a0r, off);
        a0i += __shfl_down(a0i, off);
        a1r += __shfl_down(a1r, off);
        a1i += __shfl_down(a1i, off);
    }
    __shared__ float4 sred[4];
    int wid = threadIdx.x >> 6;
    int lane = threadIdx.x & 63;
    if (lane == 0) sred[wid] = make_float4(a0r, a0i, a1r, a1i);
    __syncthreads();
    if (threadIdx.x == 0) {
        float4 t = sred[0];
        t.x += sred[1].x + sred[2].x + sred[3].x;
        t.y += sred[1].y + sred[2].y + sred[3].y;
        t.z += sred[1].z + sred[2].z + sred[3].z;
        t.w += sred[1].w + sred[2].w + sred[3].w;
        float gamma = sqrtf(1.f - __expf(-2.f * nu));
        float br0 = B_re[2 * n] * gamma, bi0 = B_im[2 * n] * gamma;
        float br1 = B_re[2 * n + 1] * gamma, bi1 = B_im[2 * n + 1] * gamma;
        float str = t.x * br0 - t.y * bi0 + t.z * br1 - t.w * bi1;
        float sti = t.x * bi0 + t.y * br0 + t.z * bi1 + t.w * br1;
        float2 cw = Cw[n];
        float gval = str * cw.x - sti * cw.y;        // Re(state * Cw[n])
        unsafeAtomicAdd(&out[b], gval);              // native global_atomic_add_f32
    }
}

extern "C" void kernel_launch(void* const* d_in, const int* in_sizes, int n_in,
                              void* d_out, int out_size, void* d_ws, size_t ws_size,
                              hipStream_t stream) {
    const float* x         = (const float*)d_in[0];
    const int*   lengths   = (const int*)d_in[1];
    const float* nu_log    = (const float*)d_in[2];
    const float* theta_log = (const float*)d_in[3];
    const float* B_re      = (const float*)d_in[4];
    const float* B_im      = (const float*)d_in[5];
    const float* C_re      = (const float*)d_in[6];
    const float* C_im      = (const float*)d_in[7];
    const float* D         = (const float*)d_in[8];
    const float* Wh        = (const float*)d_in[9];
    const float* bh        = (const float*)d_in[10];
    float* out = (float*)d_out;

    float2* Cw = (float2*)d_ws;  // N_ float2

    setup_kernel<<<N_ + B_, 256, 0, stream>>>(C_re, C_im, Wh, bh, D, x, lengths,
                                              Cw, out);
    lru_kernel<<<dim3(N_, B_), 256, 0, stream>>>(x, lengths, nu_log, theta_log,
                                                 B_re, B_im, Cw, out);
}

// Round 3
// 87.503 us; speedup vs baseline: 1.5078x; 1.5078x over previous
//
#include <hip/hip_runtime.h>
#include <hip/hip_bf16.h>

#define B_ 16
#define T_ 4096
#define IN_ 2
#define H_ 256
#define N_ 256

#define TWO_PI_F 6.28318530717958647692f
#define INV_TWO_PI_D 0.15915494309189533576888376337251

// ---------------------------------------------------------------------------
// Kernel 1: Cw[n] = sum_h Wh[h] * (C_re[h,n] + i C_im[h,n])
// ---------------------------------------------------------------------------
__global__ __launch_bounds__(256) void cw_kernel(const float* __restrict__ C_re,
                                                 const float* __restrict__ C_im,
                                                 const float* __restrict__ Wh,
                                                 float2* __restrict__ Cw) {
    int n = blockIdx.x;
    int h = threadIdx.x;
    float w = Wh[h];
    float vr = w * C_re[h * N_ + n];
    float vi = w * C_im[h * N_ + n];
    for (int off = 32; off > 0; off >>= 1) {
        vr += __shfl_down(vr, off);
        vi += __shfl_down(vi, off);
    }
    __shared__ float2 sred[4];
    int wid = threadIdx.x >> 6;
    int lane = threadIdx.x & 63;
    if (lane == 0) sred[wid] = make_float2(vr, vi);
    __syncthreads();
    if (threadIdx.x == 0) {
        float2 t = sred[0];
        t.x += sred[1].x + sred[2].x + sred[3].x;
        t.y += sred[1].y + sred[2].y + sred[3].y;
        Cw[n] = t;
    }
}

// ---------------------------------------------------------------------------
// Kernel 2: per (n,b): w_i = sum_{s<=t*} lam_n^{t*-s} x[b,s,i], then
// g[b,n] = Re( gamma*(Bm0*w0 + Bm1*w1) * Cw[n] ).
// Thread tid owns s ≡ tid (mod 256). COMPILE-TIME 16 iterations (full unroll:
// all 16 loads issued up front, one vmcnt wait) with clamped address +
// predicated accumulate for s<0. factor advances by lam^256 per step.
// ---------------------------------------------------------------------------
__global__ __launch_bounds__(256) void lru_kernel(
        const float* __restrict__ x, const int* __restrict__ lengths,
        const float* __restrict__ nu_log, const float* __restrict__ theta_log,
        const float* __restrict__ B_re, const float* __restrict__ B_im,
        const float2* __restrict__ Cw, float* __restrict__ g) {
    const int n = blockIdx.x;
    const int b = blockIdx.y;
    const int tid = threadIdx.x;
    const int tstar = lengths[b] - 1;

    const float nu = __expf(nu_log[n]);
    const float th = __expf(theta_log[n]);
    const double threv = (double)th * INV_TWO_PI_D;  // theta / 2pi

    const float2* xb = ((const float2*)x) + (size_t)b * T_;

    const int k0 = (tstar - tid) & 255;              // initial exponent 0..255
    const int s0 = tstar - k0;                       // s0 ≡ tid (mod 256)

    // factor = lam^k0 (fp64 phase reduction once per thread)
    double f0 = (double)k0 * threv;
    float ang0 = (float)(f0 - rint(f0)) * TWO_PI_F;
    float sn, cs;
    __sincosf(ang0, &sn, &cs);
    float e0 = __expf(-(float)k0 * nu);
    float fr = e0 * cs, fi = e0 * sn;
    // rot = lam^256
    double f2 = 256.0 * threv;
    float ang2 = (float)(f2 - rint(f2)) * TWO_PI_F;
    __sincosf(ang2, &sn, &cs);
    float e2 = __expf(-256.f * nu);                  // may underflow to 0: fine
    float rr = e2 * cs, ri = e2 * sn;

    float a0r = 0.f, a0i = 0.f, a1r = 0.f, a1i = 0.f;
#pragma unroll
    for (int j = 0; j < 16; ++j) {
        int s = s0 - 256 * j;
        int sc = s < 0 ? 0 : s;                      // clamped address
        float2 xv = xb[sc];
        if (s < 0) { xv.x = 0.f; xv.y = 0.f; }       // predicate contribution
        a0r = fmaf(fr, xv.x, a0r);
        a0i = fmaf(fi, xv.x, a0i);
        a1r = fmaf(fr, xv.y, a1r);
        a1i = fmaf(fi, xv.y, a1i);
        float nfr = fr * rr - fi * ri;               // factor *= rot
        float nfi = fmaf(fr, ri, fi * rr);
        fr = nfr;
        fi = nfi;
    }

    // block-reduce 4 floats
    for (int off = 32; off > 0; off >>= 1) {
        a0r += __shfl_down(a0r, off);
        a0i += __shfl_down(a0i, off);
        a1r += __shfl_down(a1r, off);
        a1i += __shfl_down(a1i, off);
    }
    __shared__ float4 sred[4];
    int wid = threadIdx.x >> 6;
    int lane = threadIdx.x & 63;
    if (lane == 0) sred[wid] = make_float4(a0r, a0i, a1r, a1i);
    __syncthreads();
    if (threadIdx.x == 0) {
        float4 t = sred[0];
        t.x += sred[1].x + sred[2].x + sred[3].x;
        t.y += sred[1].y + sred[2].y + sred[3].y;
        t.z += sred[1].z + sred[2].z + sred[3].z;
        t.w += sred[1].w + sred[2].w + sred[3].w;
        float gamma = sqrtf(1.f - __expf(-2.f * nu));
        float br0 = B_re[2 * n] * gamma, bi0 = B_im[2 * n] * gamma;
        float br1 = B_re[2 * n + 1] * gamma, bi1 = B_im[2 * n + 1] * gamma;
        float str = t.x * br0 - t.y * bi0 + t.z * br1 - t.w * bi1;
        float sti = t.x * bi0 + t.y * br0 + t.z * bi1 + t.w * br1;
        float2 cw = Cw[n];
        g[b * N_ + n] = str * cw.x - sti * cw.y;     // Re(state * Cw[n])
    }
}

// ---------------------------------------------------------------------------
// Kernel 3: out[b] = sum_n g[b,n] + sum_h Wh[h]*(D[h,:].x[b,t*,:]) + bh
// ---------------------------------------------------------------------------
__global__ __launch_bounds__(256) void out_kernel(
        const float* __restrict__ g, const float* __restrict__ x,
        const int* __restrict__ lengths, const float* __restrict__ D,
        const float* __restrict__ Wh, const float* __restrict__ bh,
        float* __restrict__ out) {
    int b = blockIdx.x;
    int tstar = lengths[b] - 1;
    int h = threadIdx.x;
    float2 xv = ((const float2*)x)[(size_t)b * T_ + tstar];
    float v = g[b * N_ + h] + Wh[h] * (D[2 * h] * xv.x + D[2 * h + 1] * xv.y);
    for (int off = 32; off > 0; off >>= 1) v += __shfl_down(v, off);
    __shared__ float sred[4];
    int wid = threadIdx.x >> 6;
    int lane = threadIdx.x & 63;
    if (lane == 0) sred[wid] = v;
    __syncthreads();
    if (threadIdx.x == 0) {
        out[b] = sred[0] + sred[1] + sred[2] + sred[3] + bh[0];
    }
}

extern "C" void kernel_launch(void* const* d_in, const int* in_sizes, int n_in,
                              void* d_out, int out_size, void* d_ws, size_t ws_size,
                              hipStream_t stream) {
    const float* x         = (const float*)d_in[0];
    const int*   lengths   = (const int*)d_in[1];
    const float* nu_log    = (const float*)d_in[2];
    const float* theta_log = (const float*)d_in[3];
    const float* B_re      = (const float*)d_in[4];
    const float* B_im      = (const float*)d_in[5];
    const float* C_re      = (const float*)d_in[6];
    const float* C_im      = (const float*)d_in[7];
    const float* D         = (const float*)d_in[8];
    const float* Wh        = (const float*)d_in[9];
    const float* bh        = (const float*)d_in[10];
    float* out = (float*)d_out;

    // workspace layout: [Cw: N_ float2][g: B_*N_ float]
    float2* Cw = (float2*)d_ws;
    float*  g  = (float*)d_ws + 2 * N_;

    cw_kernel<<<N_, 256, 0, stream>>>(C_re, C_im, Wh, Cw);
    lru_kernel<<<dim3(N_, B_), 256, 0, stream>>>(x, lengths, nu_log, theta_log,
                                                 B_re, B_im, Cw, g);
    out_kernel<<<B_, 256, 0, stream>>>(g, x, lengths, D, Wh, bh, out);
}

// Round 4
// 86.170 us; speedup vs baseline: 1.5311x; 1.0155x over previous
//
#include <hip/hip_runtime.h>
#include <hip/hip_bf16.h>

#define B_ 16
#define T_ 4096
#define IN_ 2
#define H_ 256
#define N_ 256

#define TWO_PI_F 6.28318530717958647692f
#define INV_TWO_PI_D 0.15915494309189533576888376337251

// ---------------------------------------------------------------------------
// Fused kernel: grid (N_/2, B_), 256 threads. Block (nb, b) handles n0=2nb,
// n1=2nb+1.
//  - Cw[n] = sum_h Wh[h]*C[h,n] computed in-block (folded into block reduce)
//  - w_i(n) = sum_{s<=t*} lam_n^{t*-s} x[b,s,i] via per-thread geometric
//    factor chains, compile-time 16 iterations (full unroll, batched loads)
//  - epilogue threads 0/1: g[b,n] = Re(gamma*(Bm0*w0+Bm1*w1) * Cw[n])
// ---------------------------------------------------------------------------
__global__ __launch_bounds__(256) void lru_fused_kernel(
        const float* __restrict__ x, const int* __restrict__ lengths,
        const float* __restrict__ nu_log, const float* __restrict__ theta_log,
        const float* __restrict__ B_re, const float* __restrict__ B_im,
        const float* __restrict__ C_re, const float* __restrict__ C_im,
        const float* __restrict__ Wh, float* __restrict__ g) {
    const int n0 = blockIdx.x * 2;
    const int n1 = n0 + 1;
    const int b = blockIdx.y;
    const int tid = threadIdx.x;
    const int tstar = lengths[b] - 1;

    // --- Cw partials (n0 even -> float2 loads of adjacent columns) ---
    float w = Wh[tid];
    float2 cre = *(const float2*)(C_re + tid * N_ + n0);
    float2 cim = *(const float2*)(C_im + tid * N_ + n0);
    float cw0r = w * cre.x, cw0i = w * cim.x;   // partial Cw[n0]
    float cw1r = w * cre.y, cw1i = w * cim.y;   // partial Cw[n1]

    // --- per-n factor setup: factor = lam^k0, rot = lam^256 ---
    const int k0 = (tstar - tid) & 255;
    const int s0 = tstar - k0;                  // s0 ≡ tid (mod 256)
    float sn, cs;

    const float nu0 = __expf(nu_log[n0]);
    const double thr0 = (double)__expf(theta_log[n0]) * INV_TWO_PI_D;
    double f0 = (double)k0 * thr0;
    __sincosf((float)(f0 - rint(f0)) * TWO_PI_F, &sn, &cs);
    float e = __expf(-(float)k0 * nu0);
    float fa_r = e * cs, fa_i = e * sn;
    double q0 = 256.0 * thr0;
    __sincosf((float)(q0 - rint(q0)) * TWO_PI_F, &sn, &cs);
    e = __expf(-256.f * nu0);
    const float ra_r = e * cs, ra_i = e * sn;

    const float nu1 = __expf(nu_log[n1]);
    const double thr1 = (double)__expf(theta_log[n1]) * INV_TWO_PI_D;
    double f1 = (double)k0 * thr1;
    __sincosf((float)(f1 - rint(f1)) * TWO_PI_F, &sn, &cs);
    e = __expf(-(float)k0 * nu1);
    float fb_r = e * cs, fb_i = e * sn;
    double q1 = 256.0 * thr1;
    __sincosf((float)(q1 - rint(q1)) * TWO_PI_F, &sn, &cs);
    e = __expf(-256.f * nu1);
    const float rb_r = e * cs, rb_i = e * sn;

    // --- main loop: 16 compile-time iterations over s = s0 - 256j ---
    const float2* xb = ((const float2*)x) + (size_t)b * T_;
    float A0r = 0.f, A0i = 0.f, A1r = 0.f, A1i = 0.f;   // n0 accumulators
    float B0r = 0.f, B0i = 0.f, B1r = 0.f, B1i = 0.f;   // n1 accumulators
#pragma unroll
    for (int j = 0; j < 16; ++j) {
        int s = s0 - 256 * j;
        int sc = s < 0 ? 0 : s;
        float2 xv = xb[sc];
        if (s < 0) { xv.x = 0.f; xv.y = 0.f; }
        A0r = fmaf(fa_r, xv.x, A0r);
        A0i = fmaf(fa_i, xv.x, A0i);
        A1r = fmaf(fa_r, xv.y, A1r);
        A1i = fmaf(fa_i, xv.y, A1i);
        B0r = fmaf(fb_r, xv.x, B0r);
        B0i = fmaf(fb_i, xv.x, B0i);
        B1r = fmaf(fb_r, xv.y, B1r);
        B1i = fmaf(fb_i, xv.y, B1i);
        float t;
        t = fa_r * ra_r - fa_i * ra_i;
        fa_i = fmaf(fa_r, ra_i, fa_i * ra_r);
        fa_r = t;
        t = fb_r * rb_r - fb_i * rb_i;
        fb_i = fmaf(fb_r, rb_i, fb_i * rb_r);
        fb_r = t;
    }

    // --- block reduce 12 floats ---
    for (int off = 32; off > 0; off >>= 1) {
        A0r += __shfl_down(A0r, off);
        A0i += __shfl_down(A0i, off);
        A1r += __shfl_down(A1r, off);
        A1i += __shfl_down(A1i, off);
        B0r += __shfl_down(B0r, off);
        B0i += __shfl_down(B0i, off);
        B1r += __shfl_down(B1r, off);
        B1i += __shfl_down(B1i, off);
        cw0r += __shfl_down(cw0r, off);
        cw0i += __shfl_down(cw0i, off);
        cw1r += __shfl_down(cw1r, off);
        cw1i += __shfl_down(cw1i, off);
    }
    __shared__ float sred[4][12];
    int wid = tid >> 6;
    int lane = tid & 63;
    if (lane == 0) {
        float* p = sred[wid];
        p[0] = A0r;  p[1] = A0i;  p[2] = A1r;  p[3] = A1i;
        p[4] = B0r;  p[5] = B0i;  p[6] = B1r;  p[7] = B1i;
        p[8] = cw0r; p[9] = cw0i; p[10] = cw1r; p[11] = cw1i;
    }
    __syncthreads();
    if (tid < 2) {
        // thread 0 -> n0 (slots 0..3, 8..9); thread 1 -> n1 (slots 4..7, 10..11)
        int base = tid * 4;
        float t0 = sred[0][base]     + sred[1][base]     + sred[2][base]     + sred[3][base];
        float t1 = sred[0][base + 1] + sred[1][base + 1] + sred[2][base + 1] + sred[3][base + 1];
        float t2 = sred[0][base + 2] + sred[1][base + 2] + sred[2][base + 2] + sred[3][base + 2];
        float t3 = sred[0][base + 3] + sred[1][base + 3] + sred[2][base + 3] + sred[3][base + 3];
        int cb = 8 + tid * 2;
        float cwr = sred[0][cb]     + sred[1][cb]     + sred[2][cb]     + sred[3][cb];
        float cwi = sred[0][cb + 1] + sred[1][cb + 1] + sred[2][cb + 1] + sred[3][cb + 1];
        int n = n0 + tid;
        float nu = __expf(nu_log[n]);
        float gamma = sqrtf(1.f - __expf(-2.f * nu));
        float br0 = B_re[2 * n] * gamma, bi0 = B_im[2 * n] * gamma;
        float br1 = B_re[2 * n + 1] * gamma, bi1 = B_im[2 * n + 1] * gamma;
        float str = t0 * br0 - t1 * bi0 + t2 * br1 - t3 * bi1;
        float sti = t0 * bi0 + t1 * br0 + t2 * bi1 + t3 * br1;
        g[b * N_ + n] = str * cwr - sti * cwi;   // Re(state * Cw[n])
    }
}

// ---------------------------------------------------------------------------
// out[b] = sum_n g[b,n] + sum_h Wh[h]*(D[h,:].x[b,t*,:]) + bh
// ---------------------------------------------------------------------------
__global__ __launch_bounds__(256) void out_kernel(
        const float* __restrict__ g, const float* __restrict__ x,
        const int* __restrict__ lengths, const float* __restrict__ D,
        const float* __restrict__ Wh, const float* __restrict__ bh,
        float* __restrict__ out) {
    int b = blockIdx.x;
    int tstar = lengths[b] - 1;
    int h = threadIdx.x;
    float2 xv = ((const float2*)x)[(size_t)b * T_ + tstar];
    float v = g[b * N_ + h] + Wh[h] * (D[2 * h] * xv.x + D[2 * h + 1] * xv.y);
    for (int off = 32; off > 0; off >>= 1) v += __shfl_down(v, off);
    __shared__ float sred[4];
    int wid = threadIdx.x >> 6;
    int lane = threadIdx.x & 63;
    if (lane == 0) sred[wid] = v;
    __syncthreads();
    if (threadIdx.x == 0) {
        out[b] = sred[0] + sred[1] + sred[2] + sred[3] + bh[0];
    }
}

extern "C" void kernel_launch(void* const* d_in, const int* in_sizes, int n_in,
                              void* d_out, int out_size, void* d_ws, size_t ws_size,
                              hipStream_t stream) {
    const float* x         = (const float*)d_in[0];
    const int*   lengths   = (const int*)d_in[1];
    const float* nu_log    = (const float*)d_in[2];
    const float* theta_log = (const float*)d_in[3];
    const float* B_re      = (const float*)d_in[4];
    const float* B_im      = (const float*)d_in[5];
    const float* C_re      = (const float*)d_in[6];
    const float* C_im      = (const float*)d_in[7];
    const float* D         = (const float*)d_in[8];
    const float* Wh        = (const float*)d_in[9];
    const float* bh        = (const float*)d_in[10];
    float* out = (float*)d_out;

    float* g = (float*)d_ws;  // [B_, N_]

    lru_fused_kernel<<<dim3(N_ / 2, B_), 256, 0, stream>>>(
        x, lengths, nu_log, theta_log, B_re, B_im, C_re, C_im, Wh, g);
    out_kernel<<<B_, 256, 0, stream>>>(g, x, lengths, D, Wh, bh, out);
}